// Round 1
// baseline (872.485 us; speedup 1.0000x reference)
//
#include <hip/hip_runtime.h>
#include <hip/hip_fp16.h>

// Problem constants (B, CLEN, QLEN, H)
constexpr int NB = 16;
constexpr int CL = 4096;
constexpr int QL = 512;
constexpr int HD = 256;

// ---------------------------------------------------------------------------
// Workspace layout (bytes):
//   qp     : q * w_cq, fp32, NB*QL*HD            @ 0         (8,388,608)
//   qd2    : q.w_q + b_q + b_cq, fp32, NB*QL     @ 8,388,608 (32,768)
//   cdot   : c.w_c + b_c, fp32, NB*CL            @ 8,421,376 (262,144)
//   rowmax : max_j s~ , fp32, NB*CL              @ 8,683,520 (262,144)
//   Mb     : fp32, NB                            @ 8,945,664
//   Zb     : fp32, NB                            @ 8,945,728
//   q2c    : fp32, NB*HD                         @ 8,945,792 (16,384)
//   sp     : s~ then p, fp16, NB*CL*QL           @ 8,962,176 (67,108,864)
// total ~76 MB
// ---------------------------------------------------------------------------

// One wave per q-row: qp = q*w_cq ; qd2 = q.w_q + b_q + b_cq
__global__ void k_prep_q(const float* __restrict__ q, const float* __restrict__ w_q,
                         const float* __restrict__ b_q, const float* __restrict__ w_cq,
                         const float* __restrict__ b_cq,
                         float* __restrict__ qp, float* __restrict__ qd2) {
    int row  = blockIdx.x * 4 + (threadIdx.x >> 6);   // b*QL + j
    int lane = threadIdx.x & 63;
    float4 qv  = ((const float4*)(q + (size_t)row * HD))[lane];
    float4 wq  = ((const float4*)w_q)[lane];
    float4 wcq = ((const float4*)w_cq)[lane];
    float4 o;
    o.x = qv.x * wcq.x; o.y = qv.y * wcq.y; o.z = qv.z * wcq.z; o.w = qv.w * wcq.w;
    ((float4*)(qp + (size_t)row * HD))[lane] = o;
    float s = qv.x * wq.x + qv.y * wq.y + qv.z * wq.z + qv.w * wq.w;
    #pragma unroll
    for (int off = 32; off; off >>= 1) s += __shfl_down(s, off, 64);
    if (lane == 0) qd2[row] = s + b_q[0] + b_cq[0];
}

// One wave per c-row: cdot = c.w_c + b_c
__global__ void k_cdot(const float* __restrict__ c, const float* __restrict__ w_c,
                       const float* __restrict__ b_c, float* __restrict__ cdot) {
    int row  = blockIdx.x * 4 + (threadIdx.x >> 6);   // b*CL + i
    int lane = threadIdx.x & 63;
    float4 cv = ((const float4*)(c + (size_t)row * HD))[lane];
    float4 wv = ((const float4*)w_c)[lane];
    float s = cv.x * wv.x + cv.y * wv.y + cv.z * wv.z + cv.w * wv.w;
    #pragma unroll
    for (int off = 32; off; off >>= 1) s += __shfl_down(s, off, 64);
    if (lane == 0) cdot[row] = s + b_c[0];
}

// GEMM1: s~[i][j] = sum_d c[i][d]*qp[j][d] + qd2[j]  -> fp16 sp
// 64x64 tile per block; thread (rg=t>>4, jg=t&15) owns rows i0+rg+16*ri,
// cols j0+jg+16*ji (strided ownership -> bank-conflict-free LDS reads).
__launch_bounds__(256)
__global__ void k_gemm1(const float* __restrict__ c, const float* __restrict__ qp,
                        const float* __restrict__ qd2, __half* __restrict__ sp) {
    __shared__ float cs[64][36];   // stride 36 floats: 16B-aligned rows
    __shared__ float qs[64][36];
    const int b  = blockIdx.z;
    const int i0 = blockIdx.y * 64;
    const int j0 = blockIdx.x * 64;
    const int t  = threadIdx.x;
    const int rg = t >> 4;         // 0..15
    const int jg = t & 15;         // 0..15
    float acc[4][4] = {};
    const float* cbase = c  + ((size_t)b * CL + i0) * HD;
    const float* qbase = qp + ((size_t)b * QL + j0) * HD;

    for (int dc = 0; dc < 8; ++dc) {           // K chunks of 32 over HD=256
        __syncthreads();
        #pragma unroll
        for (int p = 0; p < 2; ++p) {          // stage 64x32 of c and qp
            int idx = t + p * 256;
            int r = idx >> 3, c4 = idx & 7;
            float4 v = *(const float4*)(cbase + (size_t)r * HD + dc * 32 + c4 * 4);
            *(float4*)&cs[r][c4 * 4] = v;
            float4 w = *(const float4*)(qbase + (size_t)r * HD + dc * 32 + c4 * 4);
            *(float4*)&qs[r][c4 * 4] = w;
        }
        __syncthreads();
        #pragma unroll
        for (int dd = 0; dd < 32; dd += 4) {
            float4 a[4], bv[4];
            #pragma unroll
            for (int x = 0; x < 4; ++x) a[x]  = *(const float4*)&cs[rg + 16 * x][dd];
            #pragma unroll
            for (int x = 0; x < 4; ++x) bv[x] = *(const float4*)&qs[jg + 16 * x][dd];
            #pragma unroll
            for (int ri = 0; ri < 4; ++ri)
                #pragma unroll
                for (int ji = 0; ji < 4; ++ji)
                    acc[ri][ji] += a[ri].x * bv[ji].x + a[ri].y * bv[ji].y +
                                   a[ri].z * bv[ji].z + a[ri].w * bv[ji].w;
        }
    }
    float qdv[4];
    #pragma unroll
    for (int ji = 0; ji < 4; ++ji) qdv[ji] = qd2[b * QL + j0 + jg + 16 * ji];
    #pragma unroll
    for (int ri = 0; ri < 4; ++ri) {
        int i = i0 + rg + 16 * ri;
        __half* dst = sp + ((size_t)b * CL + i) * QL + j0 + jg;
        #pragma unroll
        for (int ji = 0; ji < 4; ++ji)
            dst[16 * ji] = __float2half(acc[ri][ji] + qdv[ji]);
    }
}

// Row softmax over j (512): sp <- p (normalized), rowmax <- max_j s~
__global__ void k_softmax(__half* __restrict__ sp, float* __restrict__ rowmax) {
    int row  = blockIdx.x * 4 + (threadIdx.x >> 6);  // b*CL + i
    int lane = threadIdx.x & 63;
    float4* rp = (float4*)(sp + (size_t)row * QL);
    union { float4 f; __half h[8]; } u;
    u.f = rp[lane];
    float v[8];
    #pragma unroll
    for (int k = 0; k < 8; ++k) v[k] = __half2float(u.h[k]);
    float m = v[0];
    #pragma unroll
    for (int k = 1; k < 8; ++k) m = fmaxf(m, v[k]);
    #pragma unroll
    for (int off = 32; off; off >>= 1) m = fmaxf(m, __shfl_xor(m, off, 64));
    float l = 0.f;
    #pragma unroll
    for (int k = 0; k < 8; ++k) { v[k] = __expf(v[k] - m); l += v[k]; }
    #pragma unroll
    for (int off = 32; off; off >>= 1) l += __shfl_xor(l, off, 64);
    float inv = 1.0f / l;
    #pragma unroll
    for (int k = 0; k < 8; ++k) u.h[k] = __float2half(v[k] * inv);
    rp[lane] = u.f;
    if (lane == 0) rowmax[row] = m;
}

// Per-batch M,Z over i of (rowmax + cdot); also zero-init q2c accumulators
__global__ void k_batch_mz(const float* __restrict__ rowmax, const float* __restrict__ cdot,
                           float* __restrict__ Mb, float* __restrict__ Zb,
                           float* __restrict__ q2c) {
    int b = blockIdx.x, t = threadIdx.x;
    q2c[b * HD + t] = 0.f;                      // zero accumulators (ws is poisoned)
    float vals[16];
    float m = -1e30f;
    #pragma unroll
    for (int k = 0; k < 16; ++k) {
        int i = t + k * 256;
        vals[k] = rowmax[b * CL + i] + cdot[b * CL + i];
        m = fmaxf(m, vals[k]);
    }
    __shared__ float redm[4], redz[4];
    #pragma unroll
    for (int off = 32; off; off >>= 1) m = fmaxf(m, __shfl_xor(m, off, 64));
    if ((t & 63) == 0) redm[t >> 6] = m;
    __syncthreads();
    m = fmaxf(fmaxf(redm[0], redm[1]), fmaxf(redm[2], redm[3]));
    float z = 0.f;
    #pragma unroll
    for (int k = 0; k < 16; ++k) z += __expf(vals[k] - m);
    #pragma unroll
    for (int off = 32; off; off >>= 1) z += __shfl_xor(z, off, 64);
    if ((t & 63) == 0) redz[t >> 6] = z;
    __syncthreads();
    if (t == 0) { Mb[b] = m; Zb[b] = redz[0] + redz[1] + redz[2] + redz[3]; }
}

// q2c[b][d] = sum_i softmax_i(rowmax+cdot) * c[b][i][d]  (partial + atomicAdd)
__global__ void k_q2c(const float* __restrict__ c, const float* __restrict__ rowmax,
                      const float* __restrict__ cdot, const float* __restrict__ Mb,
                      const float* __restrict__ Zb, float* __restrict__ q2c) {
    int b = blockIdx.x >> 6, slab = blockIdx.x & 63;
    int dd = threadIdx.x;
    float M = Mb[b], invZ = 1.0f / Zb[b];
    float acc = 0.f;
    for (int r = 0; r < 64; ++r) {
        int i = slab * 64 + r;
        float w = __expf(rowmax[b * CL + i] + cdot[b * CL + i] - M);
        acc += w * c[((size_t)b * CL + i) * HD + dd];
    }
    atomicAdd(&q2c[b * HD + dd], acc * invZ);
}

// GEMM2 + epilogue: c2q = p @ q ; write x = [c, c2q, c*c2q, c*q2c]
__launch_bounds__(256)
__global__ void k_gemm2(const float* __restrict__ c, const float* __restrict__ q,
                        const __half* __restrict__ sp, const float* __restrict__ q2c,
                        float* __restrict__ x) {
    __shared__ float ps[64][36];    // p tile [i][j-chunk]
    __shared__ float qs2[32][68];   // q tile [j][d-chunk]
    const int b  = blockIdx.z;
    const int i0 = blockIdx.y * 64;
    const int d0 = blockIdx.x * 64;
    const int t  = threadIdx.x;
    const int rg = t >> 4;          // row group: rows 4*rg..4*rg+3
    const int dg = t & 15;          // d group: cols dg*4..dg*4+3
    float acc[4][4] = {};

    for (int jc = 0; jc < 16; ++jc) {          // K chunks of 32 over QL=512
        __syncthreads();
        {   // stage p (fp16 -> fp32): 64 rows x 32
            int r = t >> 2, c16 = t & 3;
            union { float4 f; __half h[8]; } pu;
            pu.f = *(const float4*)(sp + ((size_t)b * CL + i0 + r) * QL + jc * 32 + c16 * 8);
            float tmp[8];
            #pragma unroll
            for (int k = 0; k < 8; ++k) tmp[k] = __half2float(pu.h[k]);
            *(float4*)&ps[r][c16 * 8]     = make_float4(tmp[0], tmp[1], tmp[2], tmp[3]);
            *(float4*)&ps[r][c16 * 8 + 4] = make_float4(tmp[4], tmp[5], tmp[6], tmp[7]);
        }
        #pragma unroll
        for (int p = 0; p < 2; ++p) {          // stage q: 32 rows x 64
            int idx = t + p * 256;
            int j = idx >> 4, c4 = idx & 15;
            float4 v = *(const float4*)(q + ((size_t)b * QL + jc * 32 + j) * HD + d0 + c4 * 4);
            *(float4*)&qs2[j][c4 * 4] = v;
        }
        __syncthreads();
        #pragma unroll
        for (int j = 0; j < 32; ++j) {
            float4 qv = *(const float4*)&qs2[j][dg * 4];
            float pv[4];
            #pragma unroll
            for (int ri = 0; ri < 4; ++ri) pv[ri] = ps[4 * rg + ri][j];
            #pragma unroll
            for (int ri = 0; ri < 4; ++ri) {
                acc[ri][0] += pv[ri] * qv.x;
                acc[ri][1] += pv[ri] * qv.y;
                acc[ri][2] += pv[ri] * qv.z;
                acc[ri][3] += pv[ri] * qv.w;
            }
        }
    }
    float4 q2cv = *(const float4*)(q2c + b * HD + d0 + dg * 4);
    #pragma unroll
    for (int ri = 0; ri < 4; ++ri) {
        int i = i0 + 4 * rg + ri;
        float* xrow = x + ((size_t)b * CL + i) * (4 * HD);
        float4 cv = *(const float4*)(c + ((size_t)b * CL + i) * HD + d0 + dg * 4);
        float4 a = make_float4(acc[ri][0], acc[ri][1], acc[ri][2], acc[ri][3]);
        *(float4*)&xrow[d0 + dg * 4] = cv;
        *(float4*)&xrow[HD + d0 + dg * 4] = a;
        *(float4*)&xrow[2 * HD + d0 + dg * 4] =
            make_float4(cv.x * a.x, cv.y * a.y, cv.z * a.z, cv.w * a.w);
        *(float4*)&xrow[3 * HD + d0 + dg * 4] =
            make_float4(cv.x * q2cv.x, cv.y * q2cv.y, cv.z * q2cv.z, cv.w * q2cv.w);
    }
}

extern "C" void kernel_launch(void* const* d_in, const int* in_sizes, int n_in,
                              void* d_out, int out_size, void* d_ws, size_t ws_size,
                              hipStream_t stream) {
    const float* c    = (const float*)d_in[0];
    const float* q    = (const float*)d_in[1];
    const float* w_c  = (const float*)d_in[2];
    const float* b_c  = (const float*)d_in[3];
    const float* w_q  = (const float*)d_in[4];
    const float* b_q  = (const float*)d_in[5];
    const float* w_cq = (const float*)d_in[6];
    const float* b_cq = (const float*)d_in[7];
    float* x = (float*)d_out;

    char* ws = (char*)d_ws;
    float*  qp     = (float*)(ws);
    float*  qd2    = (float*)(ws + 8388608);
    float*  cdot   = (float*)(ws + 8421376);
    float*  rowmax = (float*)(ws + 8683520);
    float*  Mb     = (float*)(ws + 8945664);
    float*  Zb     = (float*)(ws + 8945728);
    float*  q2c    = (float*)(ws + 8945792);
    __half* sp     = (__half*)(ws + 8962176);   // needs ~76 MB of ws total

    k_prep_q<<<NB * QL / 4, 256, 0, stream>>>(q, w_q, b_q, w_cq, b_cq, qp, qd2);
    k_cdot<<<NB * CL / 4, 256, 0, stream>>>(c, w_c, b_c, cdot);
    k_gemm1<<<dim3(QL / 64, CL / 64, NB), 256, 0, stream>>>(c, qp, qd2, sp);
    k_softmax<<<NB * CL / 4, 256, 0, stream>>>(sp, rowmax);
    k_batch_mz<<<NB, 256, 0, stream>>>(rowmax, cdot, Mb, Zb, q2c);
    k_q2c<<<NB * 64, 256, 0, stream>>>(c, rowmax, cdot, Mb, Zb, q2c);
    k_gemm2<<<dim3(HD / 64, CL / 64, NB), 256, 0, stream>>>(c, q, sp, q2c, x);
}

// Round 2
// 467.902 us; speedup vs baseline: 1.8647x; 1.8647x over previous
//
#include <hip/hip_runtime.h>
#include <hip/hip_fp16.h>

// Problem constants (B, CLEN, QLEN, H)
constexpr int NB = 16;
constexpr int CL = 4096;
constexpr int QL = 512;
constexpr int HD = 256;

typedef _Float16 f16x8 __attribute__((ext_vector_type(8)));
typedef _Float16 f16x4 __attribute__((ext_vector_type(4)));
typedef float    f32x4 __attribute__((ext_vector_type(4)));

// ---------------------------------------------------------------------------
// Workspace layout (bytes) — total 76,071,040 (same as round 1):
//   qph    : q*w_cq fp16 [b][j][d]   @ 0          (4,194,304)
//   qth    : q fp16 [b][d][j]        @ 4,194,304  (4,194,304)
//   qd2    : q.w_q+b_q+b_cq fp32     @ 8,388,608  (32,768)
//   cdot   : c.w_c+b_c fp32          @ 8,421,376  (262,144)
//   rowmax : fp32 NB*CL              @ 8,683,520  (262,144)
//   Mb     : fp32 NB                 @ 8,945,664
//   Zb     : fp32 NB                 @ 8,945,728
//   q2c    : fp32 NB*HD              @ 8,945,792  (16,384)
//   sp     : s~ then p, fp16         @ 8,962,176  (67,108,864)
// ---------------------------------------------------------------------------

// One wave per q-row: qph = fp16(q*w_cq) ; qd2 = q.w_q + b_q + b_cq
__global__ void k_prep_q(const float* __restrict__ q, const float* __restrict__ w_q,
                         const float* __restrict__ b_q, const float* __restrict__ w_cq,
                         const float* __restrict__ b_cq,
                         _Float16* __restrict__ qph, float* __restrict__ qd2) {
    int row  = blockIdx.x * 4 + (threadIdx.x >> 6);   // b*QL + j
    int lane = threadIdx.x & 63;
    float4 qv  = ((const float4*)(q + (size_t)row * HD))[lane];
    float4 wq  = ((const float4*)w_q)[lane];
    float4 wcq = ((const float4*)w_cq)[lane];
    f16x4 hv = {(_Float16)(qv.x * wcq.x), (_Float16)(qv.y * wcq.y),
                (_Float16)(qv.z * wcq.z), (_Float16)(qv.w * wcq.w)};
    *(f16x4*)(qph + (size_t)row * HD + lane * 4) = hv;
    float s = qv.x * wq.x + qv.y * wq.y + qv.z * wq.z + qv.w * wq.w;
    #pragma unroll
    for (int off = 32; off; off >>= 1) s += __shfl_down(s, off, 64);
    if (lane == 0) qd2[row] = s + b_q[0] + b_cq[0];
}

// One wave per c-row: cdot = c.w_c + b_c
__global__ void k_cdot(const float* __restrict__ c, const float* __restrict__ w_c,
                       const float* __restrict__ b_c, float* __restrict__ cdot) {
    int row  = blockIdx.x * 4 + (threadIdx.x >> 6);   // b*CL + i
    int lane = threadIdx.x & 63;
    float4 cv = ((const float4*)(c + (size_t)row * HD))[lane];
    float4 wv = ((const float4*)w_c)[lane];
    float s = cv.x * wv.x + cv.y * wv.y + cv.z * wv.z + cv.w * wv.w;
    #pragma unroll
    for (int off = 32; off; off >>= 1) s += __shfl_down(s, off, 64);
    if (lane == 0) cdot[row] = s + b_c[0];
}

// LDS transpose: qth[b][d][j] = fp16(q[b][j][d]); 64x64 tiles
__global__ void k_tq(const float* __restrict__ q, _Float16* __restrict__ qth) {
    __shared__ float tile[64][65];
    int b  = blockIdx.z;
    int d0 = blockIdx.x * 64;
    int j0 = blockIdx.y * 64;
    int t  = threadIdx.x;
    int rr = t >> 4, cseg = t & 15;
    #pragma unroll
    for (int p = 0; p < 4; ++p) {
        int r = rr + p * 16;   // j-row within tile
        float4 v = *(const float4*)(q + ((size_t)b * QL + j0 + r) * HD + d0 + cseg * 4);
        tile[r][cseg * 4 + 0] = v.x; tile[r][cseg * 4 + 1] = v.y;
        tile[r][cseg * 4 + 2] = v.z; tile[r][cseg * 4 + 3] = v.w;
    }
    __syncthreads();
    #pragma unroll
    for (int p = 0; p < 4; ++p) {
        int dr = rr + p * 16;  // d-row within tile
        f16x4 hv = {(_Float16)tile[cseg * 4 + 0][dr], (_Float16)tile[cseg * 4 + 1][dr],
                    (_Float16)tile[cseg * 4 + 2][dr], (_Float16)tile[cseg * 4 + 3][dr]};
        *(f16x4*)(qth + ((size_t)b * HD + d0 + dr) * QL + j0 + cseg * 4) = hv;
    }
}

// GEMM1 (MFMA): s~[i][j] = sum_d c[i][d]*qp[j][d] + qd2[j]  -> fp16 sp
// 128x128 tile, 4 waves in 2x2, each wave 4x4 16x16x32 fragments, K=256.
__launch_bounds__(256)
__global__ void k_gemm1(const float* __restrict__ c, const _Float16* __restrict__ qph,
                        const float* __restrict__ qd2, _Float16* __restrict__ sp) {
    __shared__ _Float16 As[128][72];   // c tile (fp16), stride 72 = 144B rows
    __shared__ _Float16 Bs[128][72];   // qph tile
    const int b  = blockIdx.z;
    const int i0 = blockIdx.y * 128;
    const int j0 = blockIdx.x * 128;
    const int t  = threadIdx.x;
    const int wave = t >> 6, wi = wave >> 1, wj = wave & 1;
    const int ln = t & 15, quad = (t >> 4) & 3;
    f32x4 acc[4][4];
    #pragma unroll
    for (int a = 0; a < 4; ++a)
        #pragma unroll
        for (int bb = 0; bb < 4; ++bb) acc[a][bb] = (f32x4){0.f, 0.f, 0.f, 0.f};

    for (int dc = 0; dc < 4; ++dc) {            // K chunks of 64 over HD=256
        __syncthreads();
        #pragma unroll
        for (int p = 0; p < 4; ++p) {           // A: 128 rows x 64 cols, fp32->fp16
            int idx = t + p * 256;
            int row = idx >> 3, g = idx & 7;
            const float* src = c + ((size_t)b * CL + i0 + row) * HD + dc * 64 + g * 8;
            float4 v0 = *(const float4*)src;
            float4 v1 = *(const float4*)(src + 4);
            f16x8 hv = {(_Float16)v0.x, (_Float16)v0.y, (_Float16)v0.z, (_Float16)v0.w,
                        (_Float16)v1.x, (_Float16)v1.y, (_Float16)v1.z, (_Float16)v1.w};
            *(f16x8*)&As[row][g * 8] = hv;
        }
        #pragma unroll
        for (int p = 0; p < 4; ++p) {           // B: 128 rows x 64 cols fp16
            int idx = t + p * 256;
            int row = idx >> 3, g = idx & 7;
            f16x8 hv = *(const f16x8*)(qph + ((size_t)b * QL + j0 + row) * HD + dc * 64 + g * 8);
            *(f16x8*)&Bs[row][g * 8] = hv;
        }
        __syncthreads();
        #pragma unroll
        for (int ks = 0; ks < 2; ++ks) {        // two k=32 MFMA steps
            f16x8 af[4], bf[4];
            #pragma unroll
            for (int it = 0; it < 4; ++it)
                af[it] = *(const f16x8*)&As[wi * 64 + it * 16 + ln][ks * 32 + quad * 8];
            #pragma unroll
            for (int jt = 0; jt < 4; ++jt)
                bf[jt] = *(const f16x8*)&Bs[wj * 64 + jt * 16 + ln][ks * 32 + quad * 8];
            #pragma unroll
            for (int it = 0; it < 4; ++it)
                #pragma unroll
                for (int jt = 0; jt < 4; ++jt)
                    acc[it][jt] = __builtin_amdgcn_mfma_f32_16x16x32_f16(af[it], bf[jt], acc[it][jt], 0, 0, 0);
        }
    }
    float qdv[4];
    #pragma unroll
    for (int jt = 0; jt < 4; ++jt) qdv[jt] = qd2[b * QL + j0 + wj * 64 + jt * 16 + ln];
    #pragma unroll
    for (int it = 0; it < 4; ++it)
        #pragma unroll
        for (int r = 0; r < 4; ++r) {
            int i = i0 + wi * 64 + it * 16 + quad * 4 + r;
            _Float16* dst = sp + ((size_t)b * CL + i) * QL + j0 + wj * 64 + ln;
            #pragma unroll
            for (int jt = 0; jt < 4; ++jt)
                dst[jt * 16] = (_Float16)(acc[it][jt][r] + qdv[jt]);
        }
}

// Row softmax over j (512): sp <- p (normalized), rowmax <- max_j s~
__global__ void k_softmax(__half* __restrict__ sp, float* __restrict__ rowmax) {
    int row  = blockIdx.x * 4 + (threadIdx.x >> 6);  // b*CL + i
    int lane = threadIdx.x & 63;
    float4* rp = (float4*)(sp + (size_t)row * QL);
    union { float4 f; __half h[8]; } u;
    u.f = rp[lane];
    float v[8];
    #pragma unroll
    for (int k = 0; k < 8; ++k) v[k] = __half2float(u.h[k]);
    float m = v[0];
    #pragma unroll
    for (int k = 1; k < 8; ++k) m = fmaxf(m, v[k]);
    #pragma unroll
    for (int off = 32; off; off >>= 1) m = fmaxf(m, __shfl_xor(m, off, 64));
    float l = 0.f;
    #pragma unroll
    for (int k = 0; k < 8; ++k) { v[k] = __expf(v[k] - m); l += v[k]; }
    #pragma unroll
    for (int off = 32; off; off >>= 1) l += __shfl_xor(l, off, 64);
    float inv = 1.0f / l;
    #pragma unroll
    for (int k = 0; k < 8; ++k) u.h[k] = __float2half(v[k] * inv);
    rp[lane] = u.f;
    if (lane == 0) rowmax[row] = m;
}

// Per-batch M,Z over i of (rowmax + cdot); also zero-init q2c accumulators
__global__ void k_batch_mz(const float* __restrict__ rowmax, const float* __restrict__ cdot,
                           float* __restrict__ Mb, float* __restrict__ Zb,
                           float* __restrict__ q2c) {
    int b = blockIdx.x, t = threadIdx.x;
    q2c[b * HD + t] = 0.f;
    float vals[16];
    float m = -1e30f;
    #pragma unroll
    for (int k = 0; k < 16; ++k) {
        int i = t + k * 256;
        vals[k] = rowmax[b * CL + i] + cdot[b * CL + i];
        m = fmaxf(m, vals[k]);
    }
    __shared__ float redm[4], redz[4];
    #pragma unroll
    for (int off = 32; off; off >>= 1) m = fmaxf(m, __shfl_xor(m, off, 64));
    if ((t & 63) == 0) redm[t >> 6] = m;
    __syncthreads();
    m = fmaxf(fmaxf(redm[0], redm[1]), fmaxf(redm[2], redm[3]));
    float z = 0.f;
    #pragma unroll
    for (int k = 0; k < 16; ++k) z += __expf(vals[k] - m);
    #pragma unroll
    for (int off = 32; off; off >>= 1) z += __shfl_xor(z, off, 64);
    if ((t & 63) == 0) redz[t >> 6] = z;
    __syncthreads();
    if (t == 0) { Mb[b] = m; Zb[b] = redz[0] + redz[1] + redz[2] + redz[3]; }
}

// q2c[b][d] = sum_i softmax_i(rowmax+cdot) * c[b][i][d]
__global__ void k_q2c(const float* __restrict__ c, const float* __restrict__ rowmax,
                      const float* __restrict__ cdot, const float* __restrict__ Mb,
                      const float* __restrict__ Zb, float* __restrict__ q2c) {
    int b = blockIdx.x >> 6, slab = blockIdx.x & 63;
    int dd = threadIdx.x;
    float M = Mb[b], invZ = 1.0f / Zb[b];
    float acc = 0.f;
    for (int r = 0; r < 64; ++r) {
        int i = slab * 64 + r;
        float w = __expf(rowmax[b * CL + i] + cdot[b * CL + i] - M);
        acc += w * c[((size_t)b * CL + i) * HD + dd];
    }
    atomicAdd(&q2c[b * HD + dd], acc * invZ);
}

// GEMM2 (MFMA) + epilogue: c2q = p @ q ; x = [c, c2q, c*c2q, c*q2c]
// A = p fp16 [i][j], B = qth fp16 [d][j]; 128(i)x128(d) tile, K=512.
__launch_bounds__(256)
__global__ void k_gemm2(const float* __restrict__ c, const _Float16* __restrict__ sp,
                        const _Float16* __restrict__ qth, const float* __restrict__ q2c,
                        float* __restrict__ x) {
    __shared__ _Float16 As[128][72];   // p tile
    __shared__ _Float16 Bs[128][72];   // qth tile
    const int b  = blockIdx.z;
    const int i0 = blockIdx.y * 128;
    const int d0 = blockIdx.x * 128;
    const int t  = threadIdx.x;
    const int wave = t >> 6, wi = wave >> 1, wj = wave & 1;
    const int ln = t & 15, quad = (t >> 4) & 3;
    f32x4 acc[4][4];
    #pragma unroll
    for (int a = 0; a < 4; ++a)
        #pragma unroll
        for (int bb = 0; bb < 4; ++bb) acc[a][bb] = (f32x4){0.f, 0.f, 0.f, 0.f};

    for (int jc = 0; jc < 8; ++jc) {            // K chunks of 64 over QL=512
        __syncthreads();
        #pragma unroll
        for (int p = 0; p < 4; ++p) {           // A: p 128 rows x 64 cols
            int idx = t + p * 256;
            int row = idx >> 3, g = idx & 7;
            f16x8 hv = *(const f16x8*)(sp + ((size_t)b * CL + i0 + row) * QL + jc * 64 + g * 8);
            *(f16x8*)&As[row][g * 8] = hv;
        }
        #pragma unroll
        for (int p = 0; p < 4; ++p) {           // B: qth 128 rows(d) x 64 cols(j)
            int idx = t + p * 256;
            int row = idx >> 3, g = idx & 7;
            f16x8 hv = *(const f16x8*)(qth + ((size_t)b * HD + d0 + row) * QL + jc * 64 + g * 8);
            *(f16x8*)&Bs[row][g * 8] = hv;
        }
        __syncthreads();
        #pragma unroll
        for (int ks = 0; ks < 2; ++ks) {
            f16x8 af[4], bf[4];
            #pragma unroll
            for (int it = 0; it < 4; ++it)
                af[it] = *(const f16x8*)&As[wi * 64 + it * 16 + ln][ks * 32 + quad * 8];
            #pragma unroll
            for (int jt = 0; jt < 4; ++jt)
                bf[jt] = *(const f16x8*)&Bs[wj * 64 + jt * 16 + ln][ks * 32 + quad * 8];
            #pragma unroll
            for (int it = 0; it < 4; ++it)
                #pragma unroll
                for (int jt = 0; jt < 4; ++jt)
                    acc[it][jt] = __builtin_amdgcn_mfma_f32_16x16x32_f16(af[it], bf[jt], acc[it][jt], 0, 0, 0);
        }
    }
    float q2cv[4];
    #pragma unroll
    for (int jt = 0; jt < 4; ++jt) q2cv[jt] = q2c[b * HD + d0 + wj * 64 + jt * 16 + ln];
    #pragma unroll
    for (int it = 0; it < 4; ++it)
        #pragma unroll
        for (int r = 0; r < 4; ++r) {
            int i = i0 + wi * 64 + it * 16 + quad * 4 + r;
            const float* crow = c + ((size_t)b * CL + i) * HD;
            float* xrow = x + ((size_t)b * CL + i) * (4 * HD);
            #pragma unroll
            for (int jt = 0; jt < 4; ++jt) {
                int d = d0 + wj * 64 + jt * 16 + ln;
                float cv = crow[d];
                float a  = acc[it][jt][r];
                xrow[d]          = cv;
                xrow[HD + d]     = a;
                xrow[2 * HD + d] = cv * a;
                xrow[3 * HD + d] = cv * q2cv[jt];
            }
        }
}

extern "C" void kernel_launch(void* const* d_in, const int* in_sizes, int n_in,
                              void* d_out, int out_size, void* d_ws, size_t ws_size,
                              hipStream_t stream) {
    const float* c    = (const float*)d_in[0];
    const float* q    = (const float*)d_in[1];
    const float* w_c  = (const float*)d_in[2];
    const float* b_c  = (const float*)d_in[3];
    const float* w_q  = (const float*)d_in[4];
    const float* b_q  = (const float*)d_in[5];
    const float* w_cq = (const float*)d_in[6];
    const float* b_cq = (const float*)d_in[7];
    float* x = (float*)d_out;

    char* ws = (char*)d_ws;
    _Float16* qph  = (_Float16*)(ws);
    _Float16* qth  = (_Float16*)(ws + 4194304);
    float*  qd2    = (float*)(ws + 8388608);
    float*  cdot   = (float*)(ws + 8421376);
    float*  rowmax = (float*)(ws + 8683520);
    float*  Mb     = (float*)(ws + 8945664);
    float*  Zb     = (float*)(ws + 8945728);
    float*  q2c    = (float*)(ws + 8945792);
    _Float16* sp   = (_Float16*)(ws + 8962176);

    k_prep_q<<<NB * QL / 4, 256, 0, stream>>>(q, w_q, b_q, w_cq, b_cq, qph, qd2);
    k_cdot<<<NB * CL / 4, 256, 0, stream>>>(c, w_c, b_c, cdot);
    k_tq<<<dim3(HD / 64, QL / 64, NB), 256, 0, stream>>>(q, qth);
    k_gemm1<<<dim3(QL / 128, CL / 128, NB), 256, 0, stream>>>(c, qph, qd2, sp);
    k_softmax<<<NB * CL / 4, 256, 0, stream>>>((__half*)sp, rowmax);
    k_batch_mz<<<NB, 256, 0, stream>>>(rowmax, cdot, Mb, Zb, q2c);
    k_q2c<<<NB * 64, 256, 0, stream>>>(c, rowmax, cdot, Mb, Zb, q2c);
    k_gemm2<<<dim3(HD / 128, CL / 128, NB), 256, 0, stream>>>(c, sp, qth, q2c, x);
}